// Round 1
// baseline (108.809 us; speedup 1.0000x reference)
//
#include <hip/hip_runtime.h>
#include <math.h>

// Problem geometry (fixed by setup_inputs):
//   carrier: (B=8, T=32768, 2*FD=258) float32, flat = 67,633,152 elements
//   real view x[b, s, f, c] = carrier[b*T*258 + s*258 + f*2 + c]
//   Registers are indexed along the T ("S") axis; freq bin 0 only (except START).
#define T_LEN   32768
#define ROW     258            // 2*FD
#define BATCH   8
#define BSTRIDE ((long long)T_LEN * ROW)

// Fixup: apply the _inject + blend logic at the (few) positions where
// sym != x. Runs AFTER the bulk d2d copy on the same stream (no race:
// stream ordering serializes the two).
__global__ void arith_greybox_fixup(const float* __restrict__ x,
                                    const float* __restrict__ blend_p,
                                    const int* __restrict__ src_p,
                                    float* __restrict__ out) {
    const int   src   = *src_p;
    const float bl    = 1.0f / (1.0f + expf(-(*blend_p)));  // sigmoid
    const float omb   = 1.0f - bl;

    const int tid      = blockIdx.x * blockDim.x + threadIdx.x;
    const int nthreads = gridDim.x * blockDim.x;

    if (src == 0) {
        // START: sym[..., :20, :, :] = 0 -> regs 0..19, ALL freq bins, both comps
        const int per_batch = 20 * ROW;              // 5160
        const int total     = BATCH * per_batch;     // 41280
        for (int i = tid; i < total; i += nthreads) {
            const int b = i / per_batch;
            const int j = i - b * per_batch;
            const long long idx = (long long)b * BSTRIDE + j;
            out[idx] = omb * x[idx];                 // sym = 0
        }
    } else if (src >= 1 && src <= 10) {
        // DIGIT: regs 2..11 at f=0 zeroed; reg (2+digit) set to (1,0)
        const int digit   = (src - 1) % 10;
        const int hot_reg = 2 + digit;
        const int total   = BATCH * 10 * 2;          // 160
        for (int i = tid; i < total; i += nthreads) {
            const int b = i / 20;
            const int r = i % 20;
            const int s = 2 + (r >> 1);
            const int c = r & 1;
            const float sym = (s == hot_reg && c == 0) ? 1.0f : 0.0f;
            const long long idx = (long long)b * BSTRIDE + (long long)s * ROW + c;
            out[idx] = omb * x[idx] + bl * sym;
        }
    } else if (src == 11 || src == 12) {
        // PLUS / MINUS: reg 1 at f=0 set to (+1,0) / (-1,0)
        const float re   = (src == 11) ? 1.0f : -1.0f;
        const int   total = BATCH * 2;               // 16
        for (int i = tid; i < total; i += nthreads) {
            const int b = i >> 1;
            const int c = i & 1;
            const float sym = (c == 0) ? re : 0.0f;
            const long long idx = (long long)b * BSTRIDE + 1LL * ROW + c;
            out[idx] = omb * x[idx] + bl * sym;
        }
    } else if (src == 13) {
        // EQUALS: regs {14,15,16,1} and 2..11 at f=0 -> sym = 0
        const int total = BATCH * 14 * 2;            // 224
        for (int i = tid; i < total; i += nthreads) {
            const int b  = i / 28;
            const int r  = i % 28;
            const int r2 = r >> 1;                   // 0..13
            const int c  = r & 1;
            // r2: 0,1,2 -> regs 14,15,16 ; 3 -> reg 1 ; 4..13 -> regs 2..11
            const int s = (r2 < 3) ? (14 + r2) : ((r2 == 3) ? 1 : (r2 - 2));
            const long long idx = (long long)b * BSTRIDE + (long long)s * ROW + c;
            out[idx] = omb * x[idx];                 // sym = 0
        }
    }
    // Any other token value: sym == x everywhere -> pure copy already correct.
}

extern "C" void kernel_launch(void* const* d_in, const int* in_sizes, int n_in,
                              void* d_out, int out_size, void* d_ws, size_t ws_size,
                              hipStream_t stream) {
    const float* x       = (const float*)d_in[0];  // carrier_freq_flat
    const float* blend_p = (const float*)d_in[1];  // symbolic_blend (scalar)
    const int*   src_p   = (const int*)d_in[2];    // src_token
    // d_in[3] = tgt_token: only participates in the None-check, unused here.
    float* out = (float*)d_out;

    const size_t bytes = (size_t)out_size * sizeof(float);

    // 1) Bulk identity copy (where sym == x, blended == x to within 1 ulp).
    hipMemcpyAsync(out, x, bytes, hipMemcpyDeviceToDevice, stream);

    // 2) Stream-ordered fixup of the few blended positions (reads d_in,
    //    overwrites the copied values; max 41,280 elements for START).
    arith_greybox_fixup<<<64, 256, 0, stream>>>(x, blend_p, src_p, out);
}